// Round 5
// baseline (200.611 us; speedup 1.0000x reference)
//
#include <hip/hip_runtime.h>

// SpikeCountLayer: out[b,s,h,w] = #{t : in[b,t,h,w]==s}
// B=32 (derived), T=1024, H*W=1024, dim_s=32.
//
// R4: two-phase, fully-sequential streaming. R1-R3 (three different compute
// structures, identical ~57 us) proved the bottleneck is the strided DRAM
// pattern (256B-1KiB segments @ 4 KiB stride -> ~2.3 TB/s effective).
// Phase A: block = (b, 32-t slab); streams its 128 KiB slab CONTIGUOUSLY
//   through two 64 KiB LDS stages (dwordx4, 1 KiB/wave-instr), transposes
//   via conflict-free ds_read_b32 columns, bitplane-popcount histogram for
//   2 pixels/thread, writes byte-packed partials (32 MiB) to d_ws coalesced.
// Phase B: block = (b, word w); sums 32 slab-partials with SWAR halfword
//   adds (sums <= 1024 < 2^16), writes each output dword exactly once.

constexpr int T_DIM   = 1024;
constexpr int HW      = 1024;            // H*W
constexpr int DIM_S   = 32;
constexpr int SLAB_T  = 32;              // t-values per phase-A block
constexpr int STAGE_T = 16;              // t-values per LDS stage (64 KiB)
constexpr int SLABS   = T_DIM / SLAB_T;  // 32
constexpr int THREADS_A = 512;
constexpr int THREADS_B = 256;

__global__ __launch_bounds__(THREADS_A) void spike_hist_partial(
    const int* __restrict__ in, unsigned* __restrict__ ws) {
    __shared__ int4 lds4[STAGE_T * HW / 4];      // 64 KiB, linear [t][px]
    int* lds_i = (int*)lds4;

    const int tid  = threadIdx.x;
    const int blk  = blockIdx.x;                 // [0, B*32)
    const int b    = blk >> 5;
    const int slab = blk & (SLABS - 1);
    const size_t in_base = (size_t)(b * T_DIM + slab * SLAB_T) * HW;

    unsigned pl[2][5];                           // bitplanes, 2 px, 32 t-bits
    #pragma unroll
    for (int c = 0; c < 2; ++c)
        #pragma unroll
        for (int j = 0; j < 5; ++j) pl[c][j] = 0u;

    #pragma unroll
    for (int stage = 0; stage < 2; ++stage) {
        if (stage) __syncthreads();              // prior stage's reads done
        // dense 64 KiB burst: 8 dwordx4 per thread, wave = 1 KiB contiguous
        const int4* __restrict__ gsrc =
            (const int4*)(in + in_base + (size_t)stage * STAGE_T * HW);
        int4 v[8];
        #pragma unroll
        for (int k = 0; k < 8; ++k) v[k] = gsrc[k * THREADS_A + tid];
        #pragma unroll
        for (int k = 0; k < 8; ++k) lds4[k * THREADS_A + tid] = v[k];
        __syncthreads();

        // transpose: my 2 pixel-columns; lanes read consecutive px -> no
        // bank conflicts (t*1024 = 0 mod 32 banks)
        #pragma unroll
        for (int c = 0; c < 2; ++c) {
            const int px = c * THREADS_A + tid;
            #pragma unroll
            for (int t = 0; t < STAGE_T; ++t) {
                const unsigned x = (unsigned)lds_i[t * HW + px];
                const int bit = stage * STAGE_T + t;
                #pragma unroll
                for (int j = 0; j < 5; ++j)
                    pl[c][j] |= ((x >> j) & 1u) << bit;
            }
        }
    }

    // popcount all 32 bins per pixel; pack 4 bins/byte-lane per dword.
    // bin s = 16*s4 + 4*j + k  ->  word w = 4*s4 + j, byte k.
    #pragma unroll
    for (int c = 0; c < 2; ++c) {
        const int px = c * THREADS_A + tid;
        const unsigned p0 = pl[c][0], p1 = pl[c][1], p2 = pl[c][2],
                       p3 = pl[c][3], p4 = pl[c][4];
        const unsigned n0 = ~p0, n1 = ~p1, n2 = ~p2, n3 = ~p3;
        const unsigned a[4]  = { n1 & n0, n1 & p0, p1 & n0, p1 & p0 };
        const unsigned bq[4] = { n3 & n2, n3 & p2, p3 & n2, p3 & p2 };
        #pragma unroll
        for (int s4 = 0; s4 < 2; ++s4) {
            const unsigned m4 = s4 ? p4 : ~p4;
            #pragma unroll
            for (int j = 0; j < 4; ++j) {
                unsigned word = 0u;
                #pragma unroll
                for (int k = 0; k < 4; ++k)
                    word |= (unsigned)__builtin_popcount(bq[j] & a[k] & m4)
                            << (k * 8);
                // coalesced: lanes have consecutive px
                ws[((size_t)(b * SLABS + slab) * 8 + (s4 * 4 + j)) * HW + px]
                    = word;
            }
        }
    }
}

__global__ __launch_bounds__(THREADS_B) void spike_hist_reduce(
    const unsigned* __restrict__ ws, int* __restrict__ out) {
    const int blk = blockIdx.x;                  // b*8 + w
    const int b   = blk >> 3;
    const int w   = blk & 7;
    const int tid = threadIdx.x;
    #pragma unroll
    for (int r = 0; r < 4; ++r) {
        const int px = r * THREADS_B + tid;
        unsigned lo = 0u, hi = 0u;
        #pragma unroll
        for (int slab = 0; slab < SLABS; ++slab) {
            const unsigned x =
                ws[((size_t)(b * SLABS + slab) * 8 + w) * HW + px];
            lo += x & 0x00FF00FFu;               // bytes 0,2 -> halfwords
            hi += (x >> 8) & 0x00FF00FFu;        // bytes 1,3 -> halfwords
        }
        int* __restrict__ op = out + ((size_t)b * DIM_S + w * 4) * HW + px;
        op[0 * HW] = (int)(lo & 0xFFFFu);        // s = 4w+0
        op[1 * HW] = (int)(hi & 0xFFFFu);        // s = 4w+1
        op[2 * HW] = (int)(lo >> 16);            // s = 4w+2
        op[3 * HW] = (int)(hi >> 16);            // s = 4w+3
    }
}

extern "C" void kernel_launch(void* const* d_in, const int* in_sizes, int n_in,
                              void* d_out, int out_size, void* d_ws, size_t ws_size,
                              hipStream_t stream) {
    const int* in = (const int*)d_in[0];
    int* out      = (int*)d_out;
    unsigned* ws  = (unsigned*)d_ws;             // needs B MiB (32 MiB @ B=32)
    const int B   = in_sizes[0] / (T_DIM * HW);  // 32 for the reference setup
    spike_hist_partial<<<B * SLABS, THREADS_A, 0, stream>>>(in, ws);
    spike_hist_reduce <<<B * 8,     THREADS_B, 0, stream>>>(ws, out);
}

// Round 6
// 192.484 us; speedup vs baseline: 1.0422x; 1.0422x over previous
//
#include <hip/hip_runtime.h>

// SpikeCountLayer: out[b,s,h,w] = #{t : in[b,t,h,w]==s}
// B=32 (derived), T=1024, H*W=1024, dim_s=32.
//
// R5: REVERT to the R3 kernel (best measured: 192.7 us total). Evidence
// from R1-R4: four structurally different kernels (cmp-select, bitplane,
// 4x-vectorized strided, fully-sequential LDS-staged + 2-phase) all land at
// kernel ~57-65 us. The profile top-5 is the harness's own 536 MB d_ws
// poison fill at 85-87% HBM peak per iteration; the kernel window is
// contended by that fill's L3 writeback drain, making kernel time
// access-pattern-invariant. The 2-phase R4 only added 64 MiB of real ws
// traffic (-> 200.6 us). This version: zero workspace traffic, dwordx4
// coalesced loads, bitplane-popcount byte-packed histogram, LDS epilogue.

constexpr int T_DIM   = 1024;
constexpr int HW      = 1024;            // H*W
constexpr int DIM_S   = 32;
constexpr int PIX_PB  = 128;             // pixels per block
constexpr int QUADS   = PIX_PB / 4;      // 32 pixel-quads per block
constexpr int THREADS = 512;
constexpr int SLICES  = THREADS / QUADS; // 16 t-slices
constexpr int T_PER_THREAD = T_DIM / SLICES;  // 64
constexpr int CHUNKS  = HW / PIX_PB;     // 8

__global__ __launch_bounds__(THREADS) void spike_hist_kernel(
    const int* __restrict__ in, int* __restrict__ out) {
    __shared__ unsigned lds[32 * THREADS];   // 64 KiB: [cw-word m][tid]

    const int tid  = threadIdx.x;
    const int quad = tid & (QUADS - 1);
    const int sl   = tid >> 5;               // t-slice
    const int blk  = blockIdx.x;
    const int b    = blk >> 3;
    const int pix0 = (blk & (CHUNKS - 1)) * PIX_PB;

    const int* __restrict__ base = in
        + (size_t)b * (T_DIM * HW)
        + (size_t)(sl * T_PER_THREAD) * HW
        + pix0 + quad * 4;

    unsigned cw[32];                         // byte-packed counts, 4 px x 8 words
    #pragma unroll
    for (int m = 0; m < 32; ++m) cw[m] = 0u;

    #pragma unroll
    for (int g = 0; g < 2; ++g) {            // two 32-t groups
        unsigned pl[4][5];                   // per-px bit-planes
        #pragma unroll
        for (int c = 0; c < 4; ++c)
            #pragma unroll
            for (int j = 0; j < 5; ++j) pl[c][j] = 0u;

        #pragma unroll
        for (int ph = 0; ph < 4; ++ph) {     // 4 phases x 8 dwordx4 loads
            int4 v[8];
            #pragma unroll
            for (int i = 0; i < 8; ++i)
                v[i] = *(const int4*)(base + (size_t)(g * 32 + ph * 8 + i) * HW);
            #pragma unroll
            for (int i = 0; i < 8; ++i) {
                const int ti = ph * 8 + i;
                const unsigned xs[4] = { (unsigned)v[i].x, (unsigned)v[i].y,
                                         (unsigned)v[i].z, (unsigned)v[i].w };
                #pragma unroll
                for (int c = 0; c < 4; ++c) {
                    const unsigned x = xs[c];
                    #pragma unroll
                    for (int j = 0; j < 5; ++j)
                        pl[c][j] |= ((x >> j) & 1u) << ti;
                }
            }
        }

        #pragma unroll
        for (int c = 0; c < 4; ++c) {
            const unsigned p0 = pl[c][0], p1 = pl[c][1], p2 = pl[c][2],
                           p3 = pl[c][3], p4 = pl[c][4];
            const unsigned n0 = ~p0, n1 = ~p1, n2 = ~p2, n3 = ~p3, n4 = ~p4;
            const unsigned a[4]  = { n1 & n0, n1 & p0, p1 & n0, p1 & p0 };
            const unsigned bq[4] = { n3 & n2, n3 & p2, p3 & n2, p3 & p2 };
            #pragma unroll
            for (int j = 0; j < 4; ++j) {
                #pragma unroll
                for (int k = 0; k < 4; ++k) {
                    const unsigned ab = bq[j] & a[k];
                    // bin j*4+k (s4=0) -> word c*8+j, byte k
                    cw[c * 8 + j]     += (unsigned)__builtin_popcount(ab & n4) << (k * 8);
                    // bin 16+j*4+k    -> word c*8+4+j, byte k
                    cw[c * 8 + 4 + j] += (unsigned)__builtin_popcount(ab & p4) << (k * 8);
                }
            }
        }
    }

    #pragma unroll
    for (int m = 0; m < 32; ++m) lds[m * THREADS + tid] = cw[m];
    __syncthreads();

    // epilogue: 1024 dword-columns (c,w,quad); 2 per thread.
    // column sum over 16 slices, halfword-packed (max 16*64=1024 < 65536).
    int* __restrict__ outb = out + (size_t)b * (DIM_S * HW) + pix0;
    #pragma unroll
    for (int k = 0; k < 2; ++k) {
        const int col = k * THREADS + tid;   // [0, 1024)
        const int q   = col & 31;            // quad
        const int m   = col >> 5;            // c*8 + w
        const int c   = m >> 3;
        const int w   = m & 7;
        unsigned lo = 0u, hi = 0u;
        #pragma unroll
        for (int s2 = 0; s2 < SLICES; ++s2) {
            const unsigned x = lds[m * THREADS + s2 * 32 + q];  // bank=q: 2-way
            lo += x & 0x00FF00FFu;
            hi += (x >> 8) & 0x00FF00FFu;
        }
        // word w packs bins s(kb) = (w>>2)*16 + (w&3)*4 + kb at byte kb
        const int s_base = (w >> 2) * 16 + (w & 3) * 4;
        const int px     = q * 4 + c;
        int* __restrict__ op = outb + (size_t)s_base * HW + px;
        op[0 * HW] = (int)(lo & 0xFFFFu);
        op[1 * HW] = (int)(hi & 0xFFFFu);
        op[2 * HW] = (int)(lo >> 16);
        op[3 * HW] = (int)(hi >> 16);
    }
}

extern "C" void kernel_launch(void* const* d_in, const int* in_sizes, int n_in,
                              void* d_out, int out_size, void* d_ws, size_t ws_size,
                              hipStream_t stream) {
    const int* in = (const int*)d_in[0];
    int* out      = (int*)d_out;
    const int B   = in_sizes[0] / (T_DIM * HW);   // 32 for the reference setup
    const int grid = B * CHUNKS;                  // 256 blocks = 1/CU
    spike_hist_kernel<<<grid, THREADS, 0, stream>>>(in, out);
}